// Round 10
// baseline (168.610 us; speedup 1.0000x reference)
//
#include <hip/hip_runtime.h>
#include <hip/hip_bf16.h>
#include <math.h>

#define BATCH 16
#define SEQ   2048
#define HID   128
#define DIM   64
#define XSP   136   // xs row pitch (ushorts)
#define QSP   68    // Q/K staging tile pitch (ushorts): 2-way max on b64/b128

typedef __attribute__((ext_vector_type(8))) short bf16x8;
typedef __attribute__((ext_vector_type(4))) float f32x4;

// 0.125 (1/sqrt(D)) * log2(e): folded into Wq so MFMA emits log2-domain scores
#define QSCALE 0.18033688011112042f
#define C0_PE  0.07195578314043169f   // ln(10000)/128

static __device__ __forceinline__ ushort f2bf(float f) {
    union { float f; unsigned u; } v; v.f = f;
    unsigned r = v.u + 0x7FFFu + ((v.u >> 16) & 1u);   // RNE
    return (ushort)(r >> 16);
}

static __device__ __forceinline__ float fast_exp2(float x) {
#if __has_builtin(__builtin_amdgcn_exp2f)
    return __builtin_amdgcn_exp2f(x);
#else
    return exp2f(x);
#endif
}

// ---------------------------------------------------------------------------
// PE table + weight prep in ONE dispatch (R9-proven).
// ---------------------------------------------------------------------------
__global__ __launch_bounds__(256) void k_peprep(
    const float* __restrict__ Wq, const float* __restrict__ Wk,
    const float* __restrict__ Wv, const float* __restrict__ Wf,
    float* __restrict__ pet, ushort* __restrict__ Wt, float* __restrict__ wvf)
{
    const int tid = threadIdx.x;
    int i = blockIdx.x * 256 + tid;              // pair index, 2048*64 total
    int pos = i >> 6, hp = i & 63;
    float ang = (float)pos * __expf(-(float)(2 * hp) * C0_PE);
    pet[pos * HID + 2 * hp]     = __sinf(ang);
    pet[pos * HID + 2 * hp + 1] = __cosf(ang);

    if (blockIdx.x == gridDim.x - 1) {
        if (tid < HID) {
            float s = 0.f;
            #pragma unroll 8
            for (int d = 0; d < DIM; ++d) s += Wv[tid * DIM + d] * Wf[d];
            wvf[tid] = s;
        }
        for (int j = tid; j < 128 * 128; j += 256) {
            int col = j >> 7, k = j & 127;
            float v = (col < 64) ? Wq[k * DIM + col] * QSCALE : Wk[k * DIM + (col - 64)];
            Wt[j] = f2bf(v);
        }
    }
}

// ---------------------------------------------------------------------------
// QKV (LDS-staged both ways): 512 thr x 512 blocks; block = 64 rows.
// Stage 1 (coalesced): xs = bf16(x + pet), vf partials.
// Stage 2: 8 waves = (rowgroup) x (Q/K half); 16 MFMAs each; acc -> qs LDS.
// Stage 3: fully-coalesced dwordx4 stores of Q/K tiles ([row][dim] layout).
// ---------------------------------------------------------------------------
__global__ __launch_bounds__(512) void k_qkv(
    const float* __restrict__ x, const float* __restrict__ pet,
    const ushort* __restrict__ Wt, const float* __restrict__ wvf,
    ushort* __restrict__ Qb, ushort* __restrict__ Kb, float* __restrict__ vf)
{
    __shared__ ushort xs[64 * XSP];      // 17.4 KB
    __shared__ float  vred[64][9];       // 2.3 KB
    __shared__ ushort qs[2][64 * QSP];   // 17.4 KB staging

    const int tid = threadIdx.x;

    // ---- Stage 1: coalesced load x+pet -> bf16 LDS, vf partial ----
    {
        const int srow = tid >> 3;               // 0..63
        const int soff = (tid & 7) * 16;         // 0..112
        const int growS = blockIdx.x * 64 + srow;
        const int posS  = growS & (SEQ - 1);
        const float4* x4 = (const float4*)(x   + (size_t)growS * HID + soff);
        const float4* p4 = (const float4*)(pet + (size_t)posS  * HID + soff);
        const float4* w4 = (const float4*)(wvf + soff);
        float vpart = 0.f;
        #pragma unroll
        for (int j = 0; j < 4; ++j) {
            float4 a = x4[j];
            float4 p = p4[j];
            float4 w = w4[j];
            float t0 = a.x + p.x, t1 = a.y + p.y, t2 = a.z + p.z, t3 = a.w + p.w;
            vpart += t0 * w.x + t1 * w.y + t2 * w.z + t3 * w.w;
            ushort4 o = {f2bf(t0), f2bf(t1), f2bf(t2), f2bf(t3)};
            *(ushort4*)&xs[srow * XSP + soff + j * 4] = o;
        }
        vred[srow][tid & 7] = vpart;
    }
    __syncthreads();

    if (tid < 64) {
        float s = 0.f;
        #pragma unroll
        for (int j = 0; j < 8; ++j) s += vred[tid][j];
        vf[blockIdx.x * 64 + tid] = s;
    }

    // ---- Stage 2: MFMA per wave, results into qs ----
    {
        const int wave = tid >> 6;
        const int lane = tid & 63;
        const int quad = lane >> 4;
        const int col  = lane & 15;
        const int rg   = wave & 3;           // row group (16 rows)
        const int half = wave >> 2;          // 0 = Q, 1 = K

        bf16x8 af[4];
        #pragma unroll
        for (int c = 0; c < 4; ++c)
            af[c] = *(const bf16x8*)&xs[(rg * 16 + col) * XSP + quad * 8 + c * 32];

        ushort* qrow = &qs[half][(rg * 16 + col) * QSP];
        #pragma unroll
        for (int t = 0; t < 4; ++t) {
            const ushort* wrow = Wt + (size_t)((half * 4 + t) * 16 + col) * 128 + quad * 8;
            f32x4 acc = {0.f, 0.f, 0.f, 0.f};
            #pragma unroll
            for (int c = 0; c < 4; ++c) {
                bf16x8 wfr = *(const bf16x8*)(wrow + c * 32);
                acc = __builtin_amdgcn_mfma_f32_16x16x32_bf16(wfr, af[c], acc, 0, 0, 0);
            }
            // D: row(quad*4+r) = outdim-in-tile, col(lane&15) = xp row
            ushort4 o = {f2bf(acc.x), f2bf(acc.y), f2bf(acc.z), f2bf(acc.w)};
            *(ushort4*)&qrow[t * 16 + quad * 4] = o;
        }
    }
    __syncthreads();

    // ---- Stage 3: coalesced stores ----
    {
        const int row = tid >> 3;            // 0..63
        const int d8  = (tid & 7) * 8;       // 0..56
        const size_t gbase = ((size_t)(blockIdx.x * 64) + row) * DIM + d8;
        bf16x8 vq = *(const bf16x8*)&qs[0][row * QSP + d8];
        bf16x8 vk = *(const bf16x8*)&qs[1][row * QSP + d8];
        *(bf16x8*)&Qb[gbase] = vq;
        *(bf16x8*)&Kb[gbase] = vk;
    }
}

// ---------------------------------------------------------------------------
// Fused attention (MFMA): block = (b, 32 k-cols), 1024 blocks, 512 thr.
// A = K-frag (m = k), B = Q rows (n = q); per-iter Q prefetch.
// Phase A: l[t][r] reg-accumulate exp2 over q; end-only reduction.
// Phase B: rs accumulates exp2*w; 2 shuffles + 1 atomicAdd per q row.
// NOTE: prefetch overreads at most 16 rows past Qb end -> lands in Kb (safe).
// ---------------------------------------------------------------------------
__global__ __launch_bounds__(512) void k_attn(
    const ushort* __restrict__ Qb, const ushort* __restrict__ Kb,
    const float* __restrict__ vf, const float* __restrict__ bfp,
    float* __restrict__ outp)
{
    const int b    = blockIdx.y;
    const int k0   = blockIdx.x * 32;
    const int tid  = threadIdx.x;
    const int wave = tid >> 6;
    const int lane = tid & 63;
    const int quad = lane >> 4;
    const int col  = lane & 15;

    __shared__ float sl[8][32];
    __shared__ float wcol[32];

    bf16x8 kf[2][2];
    {
        const ushort* Kbase = Kb + ((size_t)(b * SEQ + k0)) * DIM;
        #pragma unroll
        for (int t = 0; t < 2; ++t)
            #pragma unroll
            for (int c = 0; c < 2; ++c)
                kf[t][c] = *(const bf16x8*)(Kbase + (size_t)(t * 16 + col) * DIM + quad * 8 + c * 32);
    }

    const ushort* Qstart = Qb + ((size_t)(b * SEQ + wave * 256 + col)) * DIM + quad * 8;

    // ---- Phase A: column sums ----
    float l[2][4] = {};
    {
        const ushort* Qrow = Qstart;
        bf16x8 q0 = *(const bf16x8*)(Qrow);
        bf16x8 q1 = *(const bf16x8*)(Qrow + 32);
        for (int qi = 0; qi < 16; ++qi) {
            const ushort* nxt = Qrow + 16 * DIM;
            bf16x8 n0 = *(const bf16x8*)(nxt);
            bf16x8 n1 = *(const bf16x8*)(nxt + 32);
            #pragma unroll
            for (int t = 0; t < 2; ++t) {
                f32x4 acc = {0.f, 0.f, 0.f, 0.f};
                acc = __builtin_amdgcn_mfma_f32_16x16x32_bf16(kf[t][0], q0, acc, 0, 0, 0);
                acc = __builtin_amdgcn_mfma_f32_16x16x32_bf16(kf[t][1], q1, acc, 0, 0, 0);
                #pragma unroll
                for (int r = 0; r < 4; ++r)
                    l[t][r] += fast_exp2(acc[r]);
            }
            q0 = n0; q1 = n1; Qrow = nxt;
        }
    }
    #pragma unroll
    for (int t = 0; t < 2; ++t)
        #pragma unroll
        for (int r = 0; r < 4; ++r) {
            float v = l[t][r];
            v += __shfl_xor(v, 1); v += __shfl_xor(v, 2);
            v += __shfl_xor(v, 4); v += __shfl_xor(v, 8);
            l[t][r] = v;
        }
    if (col == 0) {
        #pragma unroll
        for (int t = 0; t < 2; ++t)
            #pragma unroll
            for (int r = 0; r < 4; ++r)
                sl[wave][t * 16 + quad * 4 + r] = l[t][r];
    }
    __syncthreads();
    if (tid < 32) {
        float ll = 0.f;
        #pragma unroll
        for (int w = 0; w < 8; ++w) ll += sl[w][tid];
        wcol[tid] = vf[(size_t)b * SEQ + k0 + tid] / ll;
    }
    __syncthreads();

    // ---- Phase B: per-q accumulate over k ----
    float wreg[2][4];
    #pragma unroll
    for (int t = 0; t < 2; ++t)
        #pragma unroll
        for (int r = 0; r < 4; ++r)
            wreg[t][r] = wcol[t * 16 + quad * 4 + r];

    const float bias = bfp[0] * (1.0f / (SEQ / 32));   // 64 k-blocks per out elem
    float* outb = outp + (size_t)b * SEQ;
    {
        const ushort* Qrow = Qstart;
        bf16x8 q0 = *(const bf16x8*)(Qrow);
        bf16x8 q1 = *(const bf16x8*)(Qrow + 32);
        for (int qi = 0; qi < 16; ++qi) {
            const ushort* nxt = Qrow + 16 * DIM;
            bf16x8 n0 = *(const bf16x8*)(nxt);
            bf16x8 n1 = *(const bf16x8*)(nxt + 32);
            float rs = 0.f;
            #pragma unroll
            for (int t = 0; t < 2; ++t) {
                f32x4 acc = {0.f, 0.f, 0.f, 0.f};
                acc = __builtin_amdgcn_mfma_f32_16x16x32_bf16(kf[t][0], q0, acc, 0, 0, 0);
                acc = __builtin_amdgcn_mfma_f32_16x16x32_bf16(kf[t][1], q1, acc, 0, 0, 0);
                #pragma unroll
                for (int r = 0; r < 4; ++r)
                    rs += fast_exp2(acc[r]) * wreg[t][r];
            }
            rs += __shfl_xor(rs, 16);
            rs += __shfl_xor(rs, 32);
            if (quad == 0)
                atomicAdd(&outb[wave * 256 + qi * 16 + col], rs + bias);
            q0 = n0; q1 = n1; Qrow = nxt;
        }
    }
}

// ---------------------------------------------------------------------------
extern "C" void kernel_launch(void* const* d_in, const int* in_sizes, int n_in,
                              void* d_out, int out_size, void* d_ws, size_t ws_size,
                              hipStream_t stream) {
    (void)in_sizes; (void)n_in; (void)ws_size;
    const float* x  = (const float*)d_in[0];
    const float* Wq = (const float*)d_in[1];
    const float* Wk = (const float*)d_in[2];
    const float* Wv = (const float*)d_in[3];
    const float* Wf = (const float*)d_in[4];
    const float* bf = (const float*)d_in[5];
    float* outp = (float*)d_out;

    float*  wvf = (float*)d_ws;                                  // 256 floats
    float*  vf  = wvf + 256;                                     // B*S
    float*  pet = vf + (size_t)BATCH * SEQ;                      // SEQ*HID
    ushort* Wt  = (ushort*)(pet + (size_t)SEQ * HID);            // 128*128
    ushort* Qb  = Wt + 128 * 128;                                // B*S*D bf16
    ushort* Kb  = Qb + (size_t)BATCH * SEQ * DIM;                // B*S*D bf16 (directly after Qb: prefetch overread safety)

    hipMemsetAsync(d_out, 0, (size_t)out_size * sizeof(float), stream);
    k_peprep<<<SEQ * (HID / 2) / 256, 256, 0, stream>>>(Wq, Wk, Wv, Wf, pet, Wt, wvf);
    k_qkv<<<BATCH * SEQ / 64, 512, 0, stream>>>(x, pet, Wt, wvf, Qb, Kb, vf);
    k_attn<<<dim3(SEQ / 32, BATCH), 512, 0, stream>>>(Qb, Kb, vf, bf, outp);
}

// Round 11
// 153.207 us; speedup vs baseline: 1.1005x; 1.1005x over previous
//
#include <hip/hip_runtime.h>
#include <hip/hip_bf16.h>
#include <math.h>

#define BATCH 16
#define SEQ   2048
#define HID   128
#define DIM   64
#define XSP   136   // xs row pitch (ushorts)
#define QSP   68    // Q/K staging tile pitch (ushorts)

typedef __attribute__((ext_vector_type(8))) short bf16x8;
typedef __attribute__((ext_vector_type(4))) float f32x4;

// 0.125 (1/sqrt(D)) * log2(e): folded into Wq so MFMA emits log2-domain scores
#define QSCALE 0.18033688011112042f
#define C0_PE  0.07195578314043169f   // ln(10000)/128

static __device__ __forceinline__ ushort f2bf(float f) {
    union { float f; unsigned u; } v; v.f = f;
    unsigned r = v.u + 0x7FFFu + ((v.u >> 16) & 1u);   // RNE
    return (ushort)(r >> 16);
}

static __device__ __forceinline__ float fast_exp2(float x) {
#if __has_builtin(__builtin_amdgcn_exp2f)
    return __builtin_amdgcn_exp2f(x);
#else
    return exp2f(x);
#endif
}

// ---------------------------------------------------------------------------
// PE table + weight prep in ONE dispatch (R9-proven).
// ---------------------------------------------------------------------------
__global__ __launch_bounds__(256) void k_peprep(
    const float* __restrict__ Wq, const float* __restrict__ Wk,
    const float* __restrict__ Wv, const float* __restrict__ Wf,
    float* __restrict__ pet, ushort* __restrict__ Wt, float* __restrict__ wvf)
{
    const int tid = threadIdx.x;
    int i = blockIdx.x * 256 + tid;              // pair index, 2048*64 total
    int pos = i >> 6, hp = i & 63;
    float ang = (float)pos * __expf(-(float)(2 * hp) * C0_PE);
    pet[pos * HID + 2 * hp]     = __sinf(ang);
    pet[pos * HID + 2 * hp + 1] = __cosf(ang);

    if (blockIdx.x == gridDim.x - 1) {
        if (tid < HID) {
            float s = 0.f;
            #pragma unroll 8
            for (int d = 0; d < DIM; ++d) s += Wv[tid * DIM + d] * Wf[d];
            wvf[tid] = s;
        }
        for (int j = tid; j < 128 * 128; j += 256) {
            int col = j >> 7, k = j & 127;
            float v = (col < 64) ? Wq[k * DIM + col] * QSCALE : Wk[k * DIM + (col - 64)];
            Wt[j] = f2bf(v);
        }
    }
}

// ---------------------------------------------------------------------------
// QKV (LDS-staged both ways, R10 version unchanged): 512 thr x 512 blocks.
// ---------------------------------------------------------------------------
__global__ __launch_bounds__(512) void k_qkv(
    const float* __restrict__ x, const float* __restrict__ pet,
    const ushort* __restrict__ Wt, const float* __restrict__ wvf,
    ushort* __restrict__ Qb, ushort* __restrict__ Kb, float* __restrict__ vf)
{
    __shared__ ushort xs[64 * XSP];      // 17.4 KB
    __shared__ float  vred[64][9];       // 2.3 KB
    __shared__ ushort qs[2][64 * QSP];   // 17.4 KB staging

    const int tid = threadIdx.x;

    // ---- Stage 1: coalesced load x+pet -> bf16 LDS, vf partial ----
    {
        const int srow = tid >> 3;               // 0..63
        const int soff = (tid & 7) * 16;         // 0..112
        const int growS = blockIdx.x * 64 + srow;
        const int posS  = growS & (SEQ - 1);
        const float4* x4 = (const float4*)(x   + (size_t)growS * HID + soff);
        const float4* p4 = (const float4*)(pet + (size_t)posS  * HID + soff);
        const float4* w4 = (const float4*)(wvf + soff);
        float vpart = 0.f;
        #pragma unroll
        for (int j = 0; j < 4; ++j) {
            float4 a = x4[j];
            float4 p = p4[j];
            float4 w = w4[j];
            float t0 = a.x + p.x, t1 = a.y + p.y, t2 = a.z + p.z, t3 = a.w + p.w;
            vpart += t0 * w.x + t1 * w.y + t2 * w.z + t3 * w.w;
            ushort4 o = {f2bf(t0), f2bf(t1), f2bf(t2), f2bf(t3)};
            *(ushort4*)&xs[srow * XSP + soff + j * 4] = o;
        }
        vred[srow][tid & 7] = vpart;
    }
    __syncthreads();

    if (tid < 64) {
        float s = 0.f;
        #pragma unroll
        for (int j = 0; j < 8; ++j) s += vred[tid][j];
        vf[blockIdx.x * 64 + tid] = s;
    }

    // ---- Stage 2: MFMA per wave, results into qs ----
    {
        const int wave = tid >> 6;
        const int lane = tid & 63;
        const int quad = lane >> 4;
        const int col  = lane & 15;
        const int rg   = wave & 3;           // row group (16 rows)
        const int half = wave >> 2;          // 0 = Q, 1 = K

        bf16x8 af[4];
        #pragma unroll
        for (int c = 0; c < 4; ++c)
            af[c] = *(const bf16x8*)&xs[(rg * 16 + col) * XSP + quad * 8 + c * 32];

        ushort* qrow = &qs[half][(rg * 16 + col) * QSP];
        #pragma unroll
        for (int t = 0; t < 4; ++t) {
            const ushort* wrow = Wt + (size_t)((half * 4 + t) * 16 + col) * 128 + quad * 8;
            f32x4 acc = {0.f, 0.f, 0.f, 0.f};
            #pragma unroll
            for (int c = 0; c < 4; ++c) {
                bf16x8 wfr = *(const bf16x8*)(wrow + c * 32);
                acc = __builtin_amdgcn_mfma_f32_16x16x32_bf16(wfr, af[c], acc, 0, 0, 0);
            }
            // D: row(quad*4+r) = outdim-in-tile, col(lane&15) = xp row
            ushort4 o = {f2bf(acc.x), f2bf(acc.y), f2bf(acc.z), f2bf(acc.w)};
            *(ushort4*)&qrow[t * 16 + quad * 4] = o;
        }
    }
    __syncthreads();

    // ---- Stage 3: coalesced stores ----
    {
        const int row = tid >> 3;            // 0..63
        const int d8  = (tid & 7) * 8;       // 0..56
        const size_t gbase = ((size_t)(blockIdx.x * 64) + row) * DIM + d8;
        bf16x8 vq = *(const bf16x8*)&qs[0][row * QSP + d8];
        bf16x8 vk = *(const bf16x8*)&qs[1][row * QSP + d8];
        *(bf16x8*)&Qb[gbase] = vq;
        *(bf16x8*)&Kb[gbase] = vk;
    }
}

// ---------------------------------------------------------------------------
// Fused attention (MFMA): block = (b, 128 k-cols), 256 blocks, 512 thr.
// A = K-frag (m = k), B = Q rows (n = q).  16 MFMAs + 32 exp2 per iter
// (2x the R7 arithmetic intensity per Q-load).
// Phase A: l[t][r] reg-accumulate exp2 over q; end-only reduction.
// Phase B: rs accumulates exp2*w; 2 shuffles + 1 atomicAdd per q row.
// ---------------------------------------------------------------------------
__global__ __launch_bounds__(512) void k_attn(
    const ushort* __restrict__ Qb, const ushort* __restrict__ Kb,
    const float* __restrict__ vf, const float* __restrict__ bfp,
    float* __restrict__ outp)
{
    const int b    = blockIdx.y;
    const int k0   = blockIdx.x * 128;
    const int tid  = threadIdx.x;
    const int wave = tid >> 6;
    const int lane = tid & 63;
    const int quad = lane >> 4;
    const int col  = lane & 15;

    __shared__ float sl[8][128];
    __shared__ float wcol[128];

    // resident K fragments (A-side): 8 tiles x 2 chunks
    bf16x8 kf[8][2];
    {
        const ushort* Kbase = Kb + ((size_t)(b * SEQ + k0)) * DIM;
        #pragma unroll
        for (int t = 0; t < 8; ++t)
            #pragma unroll
            for (int c = 0; c < 2; ++c)
                kf[t][c] = *(const bf16x8*)(Kbase + (size_t)(t * 16 + col) * DIM + quad * 8 + c * 32);
    }

    const ushort* Qstart = Qb + ((size_t)(b * SEQ + wave * 256 + col)) * DIM + quad * 8;

    // ---- Phase A: column sums ----
    float l[8][4] = {};
    {
        const ushort* Qrow = Qstart;
        for (int qi = 0; qi < 16; ++qi) {
            bf16x8 q0 = *(const bf16x8*)(Qrow);
            bf16x8 q1 = *(const bf16x8*)(Qrow + 32);
            Qrow += 16 * DIM;
            #pragma unroll
            for (int t = 0; t < 8; ++t) {
                f32x4 acc = {0.f, 0.f, 0.f, 0.f};
                acc = __builtin_amdgcn_mfma_f32_16x16x32_bf16(kf[t][0], q0, acc, 0, 0, 0);
                acc = __builtin_amdgcn_mfma_f32_16x16x32_bf16(kf[t][1], q1, acc, 0, 0, 0);
                #pragma unroll
                for (int r = 0; r < 4; ++r)
                    l[t][r] += fast_exp2(acc[r]);
            }
        }
    }
    #pragma unroll
    for (int t = 0; t < 8; ++t)
        #pragma unroll
        for (int r = 0; r < 4; ++r) {
            float v = l[t][r];
            v += __shfl_xor(v, 1); v += __shfl_xor(v, 2);
            v += __shfl_xor(v, 4); v += __shfl_xor(v, 8);
            l[t][r] = v;
        }
    if (col == 0) {
        #pragma unroll
        for (int t = 0; t < 8; ++t)
            #pragma unroll
            for (int r = 0; r < 4; ++r)
                sl[wave][t * 16 + quad * 4 + r] = l[t][r];
    }
    __syncthreads();
    if (tid < 128) {
        float ll = 0.f;
        #pragma unroll
        for (int w = 0; w < 8; ++w) ll += sl[w][tid];
        wcol[tid] = vf[(size_t)b * SEQ + k0 + tid] / ll;
    }
    __syncthreads();

    // ---- Phase B: per-q accumulate over k ----
    float wreg[8][4];
    #pragma unroll
    for (int t = 0; t < 8; ++t)
        #pragma unroll
        for (int r = 0; r < 4; ++r)
            wreg[t][r] = wcol[t * 16 + quad * 4 + r];

    const float bias = bfp[0] * (1.0f / (SEQ / 128));   // 16 k-blocks per out elem
    float* outb = outp + (size_t)b * SEQ;
    {
        const ushort* Qrow = Qstart;
        for (int qi = 0; qi < 16; ++qi) {
            bf16x8 q0 = *(const bf16x8*)(Qrow);
            bf16x8 q1 = *(const bf16x8*)(Qrow + 32);
            Qrow += 16 * DIM;
            float rs = 0.f;
            #pragma unroll
            for (int t = 0; t < 8; ++t) {
                f32x4 acc = {0.f, 0.f, 0.f, 0.f};
                acc = __builtin_amdgcn_mfma_f32_16x16x32_bf16(kf[t][0], q0, acc, 0, 0, 0);
                acc = __builtin_amdgcn_mfma_f32_16x16x32_bf16(kf[t][1], q1, acc, 0, 0, 0);
                #pragma unroll
                for (int r = 0; r < 4; ++r)
                    rs += fast_exp2(acc[r]) * wreg[t][r];
            }
            rs += __shfl_xor(rs, 16);
            rs += __shfl_xor(rs, 32);
            if (quad == 0)
                atomicAdd(&outb[wave * 256 + qi * 16 + col], rs + bias);
        }
    }
}

// ---------------------------------------------------------------------------
extern "C" void kernel_launch(void* const* d_in, const int* in_sizes, int n_in,
                              void* d_out, int out_size, void* d_ws, size_t ws_size,
                              hipStream_t stream) {
    (void)in_sizes; (void)n_in; (void)ws_size;
    const float* x  = (const float*)d_in[0];
    const float* Wq = (const float*)d_in[1];
    const float* Wk = (const float*)d_in[2];
    const float* Wv = (const float*)d_in[3];
    const float* Wf = (const float*)d_in[4];
    const float* bf = (const float*)d_in[5];
    float* outp = (float*)d_out;

    float*  wvf = (float*)d_ws;                                  // 256 floats
    float*  vf  = wvf + 256;                                     // B*S
    float*  pet = vf + (size_t)BATCH * SEQ;                      // SEQ*HID
    ushort* Wt  = (ushort*)(pet + (size_t)SEQ * HID);            // 128*128
    ushort* Qb  = Wt + 128 * 128;                                // B*S*D bf16
    ushort* Kb  = Qb + (size_t)BATCH * SEQ * DIM;                // B*S*D bf16

    hipMemsetAsync(d_out, 0, (size_t)out_size * sizeof(float), stream);
    k_peprep<<<SEQ * (HID / 2) / 256, 256, 0, stream>>>(Wq, Wk, Wv, Wf, pet, Wt, wvf);
    k_qkv<<<BATCH * SEQ / 64, 512, 0, stream>>>(x, pet, Wt, wvf, Qb, Kb, vf);
    k_attn<<<dim3(SEQ / 128, BATCH), 512, 0, stream>>>(Qb, Kb, vf, bf, outp);
}